// Round 10
// baseline (427.212 us; speedup 1.0000x reference)
//
#include <hip/hip_runtime.h>
#include <hip/hip_bf16.h>

// DynamicBlockSparseMoE: top-4-of-16 expert block-sparse MoE.
// memset colsum -> cvt+colsum(atomic) -> gate top4 -> merged gather(w,agg) ->
// GEMM1 -> GEMM2(+bias). GEMMs: 128x256 tile, BK=32, 8 waves (64x64/wave),
// 3-buffer LDS rotation (72KB -> 2 WG/CU), counted vmcnt(3), 16x16x32 MFMA.

#define BATCH 4096
#define DIN 4096
#define NE 16
#define HD 1024
#define TOPK 4
#define TOTC (NE * HD)

using bf16 = __hip_bfloat16;
typedef __attribute__((ext_vector_type(8))) short short8;
typedef __attribute__((ext_vector_type(4))) float f32x4;

__device__ inline short f2bs(float f) {
  __hip_bfloat16 h = __float2bfloat16(f);
  return *reinterpret_cast<short*>(&h);
}

// ---- fused bf16 convert + column-sum (atomic) ------------------------------
__global__ void k_cvtsum(const float* __restrict__ x, bf16* __restrict__ xb,
                         float* __restrict__ colsum) {
  const int t = threadIdx.x;
  const int lane = t & 63;
  const int w = t >> 6;  // 0..3
  const int c = blockIdx.x * 256 + lane * 4;
  const int r0 = blockIdx.y * 128 + w * 32;
  float4 s = {0.f, 0.f, 0.f, 0.f};
  for (int i = 0; i < 32; ++i) {
    size_t off = (size_t)(r0 + i) * DIN + c;
    float4 v = *reinterpret_cast<const float4*>(x + off);
    s.x += v.x; s.y += v.y; s.z += v.z; s.w += v.w;
    ushort4 b;
    b.x = (unsigned short)f2bs(v.x); b.y = (unsigned short)f2bs(v.y);
    b.z = (unsigned short)f2bs(v.z); b.w = (unsigned short)f2bs(v.w);
    *reinterpret_cast<ushort4*>(reinterpret_cast<char*>(xb) + off * 2) = b;
  }
  __shared__ float sm[4][256];
  sm[w][lane * 4 + 0] = s.x; sm[w][lane * 4 + 1] = s.y;
  sm[w][lane * 4 + 2] = s.z; sm[w][lane * 4 + 3] = s.w;
  __syncthreads();
  float tot = sm[0][t] + sm[1][t] + sm[2][t] + sm[3][t];
  atomicAdd(&colsum[blockIdx.x * 256 + t], tot);
}

__global__ void k_gate(const float* __restrict__ colsum, const float* __restrict__ gw,
                       const float* __restrict__ gb, int* __restrict__ ids) {
  __shared__ float red[4][16];
  __shared__ float gs[16];
  int t = threadIdx.x;
  int e = t & 15, kg = t >> 4;
  float p = 0.f;
  for (int k = kg; k < DIN; k += 16) p += colsum[k] * gw[(size_t)k * NE + e];
  p += __shfl_down(p, 32);
  p += __shfl_down(p, 16);
  if ((t & 63) < 16) red[t >> 6][e] = p;
  __syncthreads();
  if (t < 16) gs[t] = red[0][t] + red[1][t] + red[2][t] + red[3][t] + (float)BATCH * gb[t];
  __syncthreads();
  if (t == 0) {
    float v[16];
    #pragma unroll
    for (int i = 0; i < 16; ++i) v[i] = gs[i];
    for (int j = 0; j < TOPK; ++j) {
      int bi = 0;
      float bv = v[0];
      for (int i2 = 1; i2 < 16; ++i2)
        if (v[i2] > bv) { bv = v[i2]; bi = i2; }
      ids[j] = bi;
      v[bi] = -3.4e38f;
    }
  }
}

// ---- merged gather: 8192 tiles (0-4095 = weight, 4096-8191 = agg_w) --------
__global__ void k_gather(const float* __restrict__ w, const float* __restrict__ a,
                         const int* __restrict__ ids,
                         bf16* __restrict__ wbt, bf16* __restrict__ abt) {
  __shared__ float tile[64 * 65];
  const int t = threadIdx.x;
  const int tc = t & 15, kr = t >> 4;
  const int tk = t & 7, nr0 = t >> 3;
  for (int tl = blockIdx.x; tl < 8192; tl += 2048) {
    const int wsel = tl < 4096;
    const int tidx = wsel ? tl : tl - 4096;
    const int k0 = (tidx & 63) * 64, n0 = (tidx >> 6) * 64;
    if (wsel) {
      const int e = ids[n0 >> 10];
      const int wc0 = e * HD + (n0 & 1023);
      #pragma unroll
      for (int j = 0; j < 4; ++j) {
        int kk = kr + j * 16;
        float4 v = *reinterpret_cast<const float4*>(w + (size_t)(k0 + kk) * TOTC + wc0 + tc * 4);
        float* dst = &tile[kk * 65 + tc * 4];
        dst[0] = v.x; dst[1] = v.y; dst[2] = v.z; dst[3] = v.w;
      }
    } else {
      const int e = ids[k0 >> 10];
      const int ar0 = e * HD + (k0 & 1023);
      #pragma unroll
      for (int j = 0; j < 4; ++j) {
        int kk = kr + j * 16;
        float4 v = *reinterpret_cast<const float4*>(a + (size_t)(ar0 + kk) * 4096 + n0 + tc * 4);
        float* dst = &tile[kk * 65 + tc * 4];
        dst[0] = v.x; dst[1] = v.y; dst[2] = v.z; dst[3] = v.w;
      }
    }
    __syncthreads();
    bf16* dstp = wsel ? wbt : abt;
    #pragma unroll
    for (int i = 0; i < 2; ++i) {
      int n = n0 + nr0 + i * 32;
      short8 r;
      #pragma unroll
      for (int m = 0; m < 8; ++m) r[m] = f2bs(tile[(tk * 8 + m) * 65 + nr0 + i * 32]);
      *reinterpret_cast<short8*>(dstp + (size_t)n * DIN + k0 + tk * 8) = r;
    }
    __syncthreads();
  }
}

// ---- GEMM: 128x256 tile, BK=32, 8 waves, 3-buf rotation, 2 WG/CU -----------
#define MFMA_BF16 __builtin_amdgcn_mfma_f32_16x16x32_bf16
#define VM3 asm volatile("s_waitcnt vmcnt(3)" ::: "memory")
#define VM0 asm volatile("s_waitcnt vmcnt(0)" ::: "memory")
#define NOST ((void)0)

// One iteration = one K-tile: 8 ds_reads + stage(t+2) + gate -> barrier ->
// lgkm(0) -> 16 MFMA -> barrier. BC = current buffer, STG/GATE per position.
#define ITER(BC, STG, GATE)                                                     \
  do {                                                                          \
    short8 af0 = LDA(BC, 0), af1 = LDA(BC, 1), af2 = LDA(BC, 2), af3 = LDA(BC, 3); \
    short8 bf0 = LDB(BC, 0), bf1 = LDB(BC, 1), bf2 = LDB(BC, 2), bf3 = LDB(BC, 3); \
    STG;                                                                        \
    GATE;                                                                       \
    __builtin_amdgcn_sched_barrier(0);                                          \
    __builtin_amdgcn_s_barrier();                                               \
    asm volatile("s_waitcnt lgkmcnt(0)" ::: "memory");                          \
    __builtin_amdgcn_sched_barrier(0);                                          \
    __builtin_amdgcn_s_setprio(1);                                              \
    acc[0][0] = MFMA_BF16(af0, bf0, acc[0][0], 0, 0, 0);                        \
    acc[0][1] = MFMA_BF16(af0, bf1, acc[0][1], 0, 0, 0);                        \
    acc[0][2] = MFMA_BF16(af0, bf2, acc[0][2], 0, 0, 0);                        \
    acc[0][3] = MFMA_BF16(af0, bf3, acc[0][3], 0, 0, 0);                        \
    acc[1][0] = MFMA_BF16(af1, bf0, acc[1][0], 0, 0, 0);                        \
    acc[1][1] = MFMA_BF16(af1, bf1, acc[1][1], 0, 0, 0);                        \
    acc[1][2] = MFMA_BF16(af1, bf2, acc[1][2], 0, 0, 0);                        \
    acc[1][3] = MFMA_BF16(af1, bf3, acc[1][3], 0, 0, 0);                        \
    acc[2][0] = MFMA_BF16(af2, bf0, acc[2][0], 0, 0, 0);                        \
    acc[2][1] = MFMA_BF16(af2, bf1, acc[2][1], 0, 0, 0);                        \
    acc[2][2] = MFMA_BF16(af2, bf2, acc[2][2], 0, 0, 0);                        \
    acc[2][3] = MFMA_BF16(af2, bf3, acc[2][3], 0, 0, 0);                        \
    acc[3][0] = MFMA_BF16(af3, bf0, acc[3][0], 0, 0, 0);                        \
    acc[3][1] = MFMA_BF16(af3, bf1, acc[3][1], 0, 0, 0);                        \
    acc[3][2] = MFMA_BF16(af3, bf2, acc[3][2], 0, 0, 0);                        \
    acc[3][3] = MFMA_BF16(af3, bf3, acc[3][3], 0, 0, 0);                        \
    __builtin_amdgcn_s_setprio(0);                                              \
    __builtin_amdgcn_s_barrier();                                               \
  } while (0)

template <int STORE_F32>
__global__ __launch_bounds__(512, 4) void k_gemm3(
    const bf16* __restrict__ A, const bf16* __restrict__ Bt,
    bf16* __restrict__ Cb, float* __restrict__ Cf, const float* __restrict__ bias) {
  __shared__ __align__(16) char smraw[73728];  // 3 bufs x (A 8KB + B 16KB)
  const int t = threadIdx.x;
  const int lane = t & 63;
  const int w = t >> 6;      // 0..7
  const int wr = w >> 2;     // 0..1 (64-row M slice)
  const int wc = w & 3;      // 0..3 (64-col N slice)

  // 2D-blocked XCD partition: 512 WGs = 32 M x 16 N tiles; XCD x owns an
  // 8M x 8N rectangle (A shared by 2 XCDs, B by 4).
  const int bid = blockIdx.x;
  const int xcd = bid & 7;
  const int i = bid >> 3;  // 0..63
  const int bm = ((xcd & 3) * 8 + (i & 7)) * 128;
  const int bn = ((xcd >> 2) * 8 + (i >> 3)) * 256;

  f32x4 acc[4][4] = {};

  // staging map: lane -> row sr = w*16 + (lane>>2), granule c = lane&3,
  // pre-swizzled source col granule = c ^ (sr&3). Same for A and B passes.
  const int sr = w * 16 + (lane >> 2);
  const int sc = ((lane & 3) ^ (sr & 3)) * 8;  // element offset

  auto STAGE = [&](int buf, int kt) {
    char* lb = smraw + buf * 24576 + w * 1024 + lane * 16;
    const bf16* ga = A + (size_t)(bm + sr) * 4096 + kt * 32 + sc;
    __builtin_amdgcn_global_load_lds(
        (const __attribute__((address_space(1))) void*)ga,
        (__attribute__((address_space(3))) void*)lb, 16, 0, 0);
    #pragma unroll
    for (int p = 0; p < 2; ++p) {
      const bf16* gb = Bt + (size_t)(bn + sr + p * 128) * 4096 + kt * 32 + sc;
      __builtin_amdgcn_global_load_lds(
          (const __attribute__((address_space(1))) void*)gb,
          (__attribute__((address_space(3))) void*)(lb + 8192 + p * 8192), 16, 0, 0);
    }
  };
  auto LDA = [&](int buf, int mf) -> short8 {
    int r = wr * 64 + mf * 16 + (lane & 15);
    int g = (lane >> 4) ^ (r & 3);
    return *reinterpret_cast<const short8*>(smraw + buf * 24576 + r * 64 + g * 16);
  };
  auto LDB = [&](int buf, int nf) -> short8 {
    int r = wc * 64 + nf * 16 + (lane & 15);
    int g = (lane >> 4) ^ (r & 3);
    return *reinterpret_cast<const short8*>(smraw + buf * 24576 + 8192 + r * 64 + g * 16);
  };

  // Prologue: stage tiles 0,1 (6 loads); gate t0 complete (3 left in flight).
  STAGE(0, 0);
  STAGE(1, 1);
  VM3;
  __builtin_amdgcn_s_barrier();

  // Steady: 42 groups of 3 K-tiles (t = 0..125), buffers rotate 0,1,2.
  for (int g3 = 0; g3 < 42; ++g3) {
    const int a = g3 * 3;
    ITER(0, STAGE(2, a + 2), VM3);
    ITER(1, STAGE(0, a + 3), VM3);
    ITER(2, STAGE(1, a + 4), VM3);
  }
  // Tail: t=126 (buf 0): nothing to stage; drain t=127's loads. t=127 (buf 1).
  ITER(0, NOST, VM0);
  ITER(1, NOST, NOST);

  // Epilogue: wave tile 64x64 at (wr,wc).
  const int cr = (lane >> 4) * 4;
  const int cc = lane & 15;
  #pragma unroll
  for (int mf = 0; mf < 4; ++mf) {
    #pragma unroll
    for (int nf = 0; nf < 4; ++nf) {
      int row = bm + wr * 64 + mf * 16 + cr;
      int col = bn + wc * 64 + nf * 16 + cc;
      #pragma unroll
      for (int r = 0; r < 4; ++r) {
        if constexpr (STORE_F32) {
          Cf[(size_t)(row + r) * 4096 + col] = acc[mf][nf][r] + bias[col];
        } else {
          Cb[(size_t)(row + r) * 4096 + col] = __float2bfloat16(acc[mf][nf][r]);
        }
      }
    }
  }
}

// ---- launch ----------------------------------------------------------------
extern "C" void kernel_launch(void* const* d_in, const int* in_sizes, int n_in,
                              void* d_out, int out_size, void* d_ws, size_t ws_size,
                              hipStream_t stream) {
  const float* x = (const float*)d_in[0];
  const float* gate_w = (const float*)d_in[1];
  const float* gate_b = (const float*)d_in[2];
  const float* weight = (const float*)d_in[3];
  const float* agg_w = (const float*)d_in[4];
  const float* agg_b = (const float*)d_in[5];
  float* out = (float*)d_out;
  char* ws = (char*)d_ws;

  // ws: colsum 16KB @0 | ids @16KB | mid 32MB @4MB | abt 32MB @36MB
  float* colsum = (float*)ws;
  int* ids = (int*)(ws + 16384);
  bf16* mid = (bf16*)(ws + (4u << 20));
  bf16* abt = (bf16*)(ws + (36u << 20));
  // scratch inside d_out (dead before GEMM2 writes it):
  bf16* xb = (bf16*)d_out;
  bf16* wbt = (bf16*)((char*)d_out + (32u << 20));

  hipMemsetAsync(colsum, 0, DIN * sizeof(float), stream);
  k_cvtsum<<<dim3(16, 32), 256, 0, stream>>>(x, xb, colsum);
  k_gate<<<1, 256, 0, stream>>>(colsum, gate_w, gate_b, ids);
  k_gather<<<2048, 256, 0, stream>>>(weight, agg_w, ids, wbt, abt);
  k_gemm3<0><<<512, 512, 0, stream>>>(xb, wbt, mid, nullptr, nullptr);
  k_gemm3<1><<<512, 512, 0, stream>>>(mid, abt, nullptr, out, agg_b);
}

// Round 11
// 382.454 us; speedup vs baseline: 1.1170x; 1.1170x over previous
//
#include <hip/hip_runtime.h>
#include <hip/hip_bf16.h>

// DynamicBlockSparseMoE: top-4-of-16 expert block-sparse MoE.
// memset colsum -> cvt+colsum(atomic) -> gate top4 -> merged gather(w,agg) ->
// GEMM1 -> GEMM2(+bias). GEMMs: 256x256, BK=64, 8 waves, 16x16x32 MFMA,
// 4 phases/K-tile, counted vmcnt, raw s_barrier, NO scheduling pins
// (compiler-emitted partial lgkmcnt waits interleave ds_read with MFMA).

#define BATCH 4096
#define DIN 4096
#define NE 16
#define HD 1024
#define TOPK 4
#define TOTC (NE * HD)
#define NT 64

using bf16 = __hip_bfloat16;
typedef __attribute__((ext_vector_type(8))) short short8;
typedef __attribute__((ext_vector_type(4))) float f32x4;

__device__ inline short f2bs(float f) {
  __hip_bfloat16 h = __float2bfloat16(f);
  return *reinterpret_cast<short*>(&h);
}

// ---- fused bf16 convert + column-sum (atomic) ------------------------------
__global__ void k_cvtsum(const float* __restrict__ x, bf16* __restrict__ xb,
                         float* __restrict__ colsum) {
  const int t = threadIdx.x;
  const int lane = t & 63;
  const int w = t >> 6;  // 0..3
  const int c = blockIdx.x * 256 + lane * 4;
  const int r0 = blockIdx.y * 128 + w * 32;
  float4 s = {0.f, 0.f, 0.f, 0.f};
  for (int i = 0; i < 32; ++i) {
    size_t off = (size_t)(r0 + i) * DIN + c;
    float4 v = *reinterpret_cast<const float4*>(x + off);
    s.x += v.x; s.y += v.y; s.z += v.z; s.w += v.w;
    ushort4 b;
    b.x = (unsigned short)f2bs(v.x); b.y = (unsigned short)f2bs(v.y);
    b.z = (unsigned short)f2bs(v.z); b.w = (unsigned short)f2bs(v.w);
    *reinterpret_cast<ushort4*>(reinterpret_cast<char*>(xb) + off * 2) = b;
  }
  __shared__ float sm[4][256];
  sm[w][lane * 4 + 0] = s.x; sm[w][lane * 4 + 1] = s.y;
  sm[w][lane * 4 + 2] = s.z; sm[w][lane * 4 + 3] = s.w;
  __syncthreads();
  float tot = sm[0][t] + sm[1][t] + sm[2][t] + sm[3][t];
  atomicAdd(&colsum[blockIdx.x * 256 + t], tot);
}

__global__ void k_gate(const float* __restrict__ colsum, const float* __restrict__ gw,
                       const float* __restrict__ gb, int* __restrict__ ids) {
  __shared__ float red[4][16];
  __shared__ float gs[16];
  int t = threadIdx.x;
  int e = t & 15, kg = t >> 4;
  float p = 0.f;
  for (int k = kg; k < DIN; k += 16) p += colsum[k] * gw[(size_t)k * NE + e];
  p += __shfl_down(p, 32);
  p += __shfl_down(p, 16);
  if ((t & 63) < 16) red[t >> 6][e] = p;
  __syncthreads();
  if (t < 16) gs[t] = red[0][t] + red[1][t] + red[2][t] + red[3][t] + (float)BATCH * gb[t];
  __syncthreads();
  if (t == 0) {
    float v[16];
    #pragma unroll
    for (int i = 0; i < 16; ++i) v[i] = gs[i];
    for (int j = 0; j < TOPK; ++j) {
      int bi = 0;
      float bv = v[0];
      for (int i2 = 1; i2 < 16; ++i2)
        if (v[i2] > bv) { bv = v[i2]; bi = i2; }
      ids[j] = bi;
      v[bi] = -3.4e38f;
    }
  }
}

// ---- merged gather: 8192 tiles (0-4095 = weight, 4096-8191 = agg_w) --------
__global__ void k_gather(const float* __restrict__ w, const float* __restrict__ a,
                         const int* __restrict__ ids,
                         bf16* __restrict__ wbt, bf16* __restrict__ abt) {
  __shared__ float tile[64 * 65];
  const int t = threadIdx.x;
  const int tc = t & 15, kr = t >> 4;
  const int tk = t & 7, nr0 = t >> 3;
  for (int tl = blockIdx.x; tl < 8192; tl += 2048) {
    const int wsel = tl < 4096;
    const int tidx = wsel ? tl : tl - 4096;
    const int k0 = (tidx & 63) * 64, n0 = (tidx >> 6) * 64;
    if (wsel) {
      const int e = ids[n0 >> 10];
      const int wc0 = e * HD + (n0 & 1023);
      #pragma unroll
      for (int j = 0; j < 4; ++j) {
        int kk = kr + j * 16;
        float4 v = *reinterpret_cast<const float4*>(w + (size_t)(k0 + kk) * TOTC + wc0 + tc * 4);
        float* dst = &tile[kk * 65 + tc * 4];
        dst[0] = v.x; dst[1] = v.y; dst[2] = v.z; dst[3] = v.w;
      }
    } else {
      const int e = ids[k0 >> 10];
      const int ar0 = e * HD + (k0 & 1023);
      #pragma unroll
      for (int j = 0; j < 4; ++j) {
        int kk = kr + j * 16;
        float4 v = *reinterpret_cast<const float4*>(a + (size_t)(ar0 + kk) * 4096 + n0 + tc * 4);
        float* dst = &tile[kk * 65 + tc * 4];
        dst[0] = v.x; dst[1] = v.y; dst[2] = v.z; dst[3] = v.w;
      }
    }
    __syncthreads();
    bf16* dstp = wsel ? wbt : abt;
    #pragma unroll
    for (int i = 0; i < 2; ++i) {
      int n = n0 + nr0 + i * 32;
      short8 r;
      #pragma unroll
      for (int m = 0; m < 8; ++m) r[m] = f2bs(tile[(tk * 8 + m) * 65 + nr0 + i * 32]);
      *reinterpret_cast<short8*>(dstp + (size_t)n * DIN + k0 + tk * 8) = r;
    }
    __syncthreads();
  }
}

// ---- GEMM: 256x256, BK=64, 8 waves, 4 phases/K-tile, UNPINNED schedule -----
#define MFMA_BF16 __builtin_amdgcn_mfma_f32_16x16x32_bf16
#define VM4 asm volatile("s_waitcnt vmcnt(4)" ::: "memory")
#define VM0 asm volatile("s_waitcnt vmcnt(0)" ::: "memory")
#define NOST ((void)0)

// Phase: ds_reads + STG + GATE -> s_barrier -> MFMA (compiler inserts partial
// lgkm waits; MFMA on frag 0 overlaps reads of frags 1..) -> s_barrier.
#define PH(BUF, Q, STG, GATE)                                                   \
  do {                                                                          \
    if ((Q) == 0) {                                                             \
      _Pragma("unroll") for (int nf = 0; nf < 4; ++nf) {                        \
        bfrag[nf][0] = LDB(BUF, nf, 0);                                         \
        bfrag[nf][1] = LDB(BUF, nf, 1);                                         \
      }                                                                         \
    }                                                                           \
    short8 aA0 = LDA(BUF, 2 * (Q), 0), aA1 = LDA(BUF, 2 * (Q), 1);              \
    short8 aB0 = LDA(BUF, 2 * (Q) + 1, 0), aB1 = LDA(BUF, 2 * (Q) + 1, 1);      \
    STG;                                                                        \
    GATE;                                                                       \
    __builtin_amdgcn_s_barrier();                                               \
    __builtin_amdgcn_s_setprio(1);                                              \
    _Pragma("unroll") for (int nf = 0; nf < 4; ++nf) {                          \
      acc[2 * (Q)][nf] = MFMA_BF16(aA0, bfrag[nf][0], acc[2 * (Q)][nf], 0, 0, 0);       \
      acc[2 * (Q)][nf] = MFMA_BF16(aA1, bfrag[nf][1], acc[2 * (Q)][nf], 0, 0, 0);       \
      acc[2 * (Q) + 1][nf] = MFMA_BF16(aB0, bfrag[nf][0], acc[2 * (Q) + 1][nf], 0, 0, 0); \
      acc[2 * (Q) + 1][nf] = MFMA_BF16(aB1, bfrag[nf][1], acc[2 * (Q) + 1][nf], 0, 0, 0); \
    }                                                                           \
    __builtin_amdgcn_s_setprio(0);                                              \
    __builtin_amdgcn_s_barrier();                                               \
  } while (0)

template <int STORE_F32>
__global__ __launch_bounds__(512, 2) void k_gemm8(
    const bf16* __restrict__ A, const bf16* __restrict__ Bt,
    bf16* __restrict__ Cb, float* __restrict__ Cf, const float* __restrict__ bias) {
  __shared__ __align__(16) char smraw[131072];
  const int t = threadIdx.x;
  const int lane = t & 63;
  const int w = t >> 6;
  const int wr = w >> 2;
  const int wc = w & 3;

  const int bid = blockIdx.x;
  const int xcd = bid & 7;
  const int i = bid >> 3;
  const int bm = ((xcd >> 1) * 4 + (i & 3)) * 256;
  const int bn = ((xcd & 1) * 8 + (i >> 2)) * 256;

  f32x4 acc[8][4] = {};
  short8 bfrag[4][2];

  const int srow = w * 16 + (lane >> 3);
  const int sgr = lane & 7;

  auto STAGE_A = [&](int buf, int half, int kt) {
    char* lb = smraw + buf * 65536 + half * 16384 + w * 2048 + lane * 16;
    #pragma unroll
    for (int i2 = 0; i2 < 2; ++i2) {
      int r = srow + i2 * 8;
      const bf16* g = A + (size_t)(bm + half * 128 + r) * 4096 + kt * 64 + ((sgr ^ (r & 7)) * 8);
      __builtin_amdgcn_global_load_lds(
          (const __attribute__((address_space(1))) void*)g,
          (__attribute__((address_space(3))) void*)(lb + i2 * 1024), 16, 0, 0);
    }
  };
  auto STAGE_B = [&](int buf, int half, int kt) {
    char* lb = smraw + buf * 65536 + 32768 + half * 16384 + w * 2048 + lane * 16;
    #pragma unroll
    for (int i2 = 0; i2 < 2; ++i2) {
      int r = srow + i2 * 8;
      const bf16* g = Bt + (size_t)(bn + half * 128 + r) * 4096 + kt * 64 + ((sgr ^ (r & 7)) * 8);
      __builtin_amdgcn_global_load_lds(
          (const __attribute__((address_space(1))) void*)g,
          (__attribute__((address_space(3))) void*)(lb + i2 * 1024), 16, 0, 0);
    }
  };
  auto LDA = [&](int buf, int mf, int kk) -> short8 {
    int r = mf * 16 + (lane & 15);
    int kb = ((kk * 4 + (lane >> 4)) ^ (r & 7)) * 16;
    return *reinterpret_cast<const short8*>(smraw + buf * 65536 + wr * 16384 + r * 128 + kb);
  };
  auto LDB = [&](int buf, int nf, int kk) -> short8 {
    int nc = wc * 64 + nf * 16 + (lane & 15);
    int half = nc >> 7, r = nc & 127;
    int kb = ((kk * 4 + (lane >> 4)) ^ (r & 7)) * 16;
    return *reinterpret_cast<const short8*>(smraw + buf * 65536 + 32768 + half * 16384 + r * 128 + kb);
  };

  // Prologue: B(0), A(0) -> buf0; B(1) -> buf1. Complete oldest 8 (B0,A0).
  STAGE_B(0, 0, 0); STAGE_B(0, 1, 0);
  STAGE_A(0, 0, 0); STAGE_A(0, 1, 0);
  STAGE_B(1, 0, 1); STAGE_B(1, 1, 1);
  VM4;
  __builtin_amdgcn_s_barrier();

  // Steady: tiles a=2t (buf0), a+1 (buf1); stages A(a+1), B(a+2), A(a+2), B(a+3).
  for (int tt = 0; tt < 31; ++tt) {
    const int a = 2 * tt;
    PH(0, 0, STAGE_A(1, 0, a + 1), NOST);
    PH(0, 1, STAGE_A(1, 1, a + 1), NOST);
    PH(0, 2, STAGE_B(0, 0, a + 2), NOST);
    PH(0, 3, STAGE_B(0, 1, a + 2), VM4);
    PH(1, 0, STAGE_A(0, 0, a + 2), NOST);
    PH(1, 1, STAGE_A(0, 1, a + 2), NOST);
    PH(1, 2, STAGE_B(1, 0, a + 3), NOST);
    PH(1, 3, STAGE_B(1, 1, a + 3), VM4);
  }
  // Tail: tiles 62 (buf0), 63 (buf1). A(63) staged in ph0-1, then drain.
  PH(0, 0, STAGE_A(1, 0, 63), NOST);
  PH(0, 1, STAGE_A(1, 1, 63), NOST);
  PH(0, 2, NOST, NOST);
  PH(0, 3, NOST, VM0);
  PH(1, 0, NOST, NOST);
  PH(1, 1, NOST, NOST);
  PH(1, 2, NOST, NOST);
  PH(1, 3, NOST, NOST);

  const int cr = (lane >> 4) * 4;
  const int cc = lane & 15;
  #pragma unroll
  for (int mf = 0; mf < 8; ++mf) {
    #pragma unroll
    for (int nf = 0; nf < 4; ++nf) {
      int row = bm + wr * 128 + mf * 16 + cr;
      int col = bn + wc * 64 + nf * 16 + cc;
      #pragma unroll
      for (int r = 0; r < 4; ++r) {
        if constexpr (STORE_F32) {
          Cf[(size_t)(row + r) * 4096 + col] = acc[mf][nf][r] + bias[col];
        } else {
          Cb[(size_t)(row + r) * 4096 + col] = __float2bfloat16(acc[mf][nf][r]);
        }
      }
    }
  }
}

// ---- launch ----------------------------------------------------------------
extern "C" void kernel_launch(void* const* d_in, const int* in_sizes, int n_in,
                              void* d_out, int out_size, void* d_ws, size_t ws_size,
                              hipStream_t stream) {
  const float* x = (const float*)d_in[0];
  const float* gate_w = (const float*)d_in[1];
  const float* gate_b = (const float*)d_in[2];
  const float* weight = (const float*)d_in[3];
  const float* agg_w = (const float*)d_in[4];
  const float* agg_b = (const float*)d_in[5];
  float* out = (float*)d_out;
  char* ws = (char*)d_ws;

  // ws: colsum 16KB @0 | ids @16KB | mid 32MB @4MB | abt 32MB @36MB
  float* colsum = (float*)ws;
  int* ids = (int*)(ws + 16384);
  bf16* mid = (bf16*)(ws + (4u << 20));
  bf16* abt = (bf16*)(ws + (36u << 20));
  // scratch inside d_out (dead before GEMM2 writes it):
  bf16* xb = (bf16*)d_out;
  bf16* wbt = (bf16*)((char*)d_out + (32u << 20));

  hipMemsetAsync(colsum, 0, DIN * sizeof(float), stream);
  k_cvtsum<<<dim3(16, 32), 256, 0, stream>>>(x, xb, colsum);
  k_gate<<<1, 256, 0, stream>>>(colsum, gate_w, gate_b, ids);
  k_gather<<<2048, 256, 0, stream>>>(weight, agg_w, ids, wbt, abt);
  k_gemm8<0><<<256, 512, 0, stream>>>(xb, wbt, mid, nullptr, nullptr);
  k_gemm8<1><<<256, 512, 0, stream>>>(mid, abt, nullptr, out, agg_b);
}